// Round 9
// baseline (142.132 us; speedup 1.0000x reference)
//
#include <hip/hip_runtime.h>
#include <math.h>

#define T_     128
#define LENM   32
#define NCOL   (8192 * 64)   // N*F = 524288 floats per timestep row
#define WSLOTS 40            // rolling window: 32 history + 8 lookahead
#define LA     8
#define CHROWS 32            // output rows per block (T split 4 ways)
#define NCHUNK (T_ / CHROWS)

typedef float f2_t __attribute__((ext_vector_type(2)));
typedef float f4_t __attribute__((ext_vector_type(4)));

// Kernel 1: build ALIGNED compact weights Wc[128][32] in d_ws.
// Wc[t][j] multiplies source row (t-31+j); zero when that row < 0.
__global__ void build_w_kernel(const float* __restrict__ M_pad,
                               const float* __restrict__ M_big,
                               float* __restrict__ Wc) {
    int t = threadIdx.x;
    if (t >= T_) return;
    const float* src;
    int len, joff;
    if (t < LENM)       { src = M_pad + t * LENM;              len = t + 1; joff = LENM - 1 - t; }
    else if (t == LENM) { src = M_pad + (LENM - 1) * LENM;     len = LENM;  joff = 0; }
    else                { src = M_big + (t - LENM - 1) * LENM; len = LENM;  joff = 0; }

    float m = -3.4e38f;
    for (int j = 0; j < len; ++j) m = fmaxf(m, src[j]);
    float e[LENM];
    float s = 0.f;
    for (int j = 0; j < len; ++j) { e[j] = expf(src[j] - m); s += e[j]; }
    float inv = 1.f / s;
    for (int j = 0; j < LENM; ++j) Wc[t * LENM + j] = 0.f;
    for (int j = 0; j < len; ++j)  Wc[t * LENM + joff + j] = e[j] * inv;
}

// Window slot for input row r in chunk C (chunk start S = C*CHROWS):
// slot = (r - S + 31) % WSLOTS  — all compile-time.

template<int C, int ROW>
__device__ __forceinline__ void load_in(const f2_t* __restrict__ xp,
                                        f2_t (&WIN)[WSLOTS]) {
    WIN[(ROW - C * CHROWS + (LENM - 1)) % WSLOTS] = xp[(size_t)ROW * (NCOL / 2)];
}

template<int C, int R0, int CNT>
__device__ __forceinline__ void load_seq(const f2_t* __restrict__ xp,
                                         f2_t (&WIN)[WSLOTS]) {
    if constexpr (CNT > 0) {
        load_in<C, R0>(xp, WIN);
        load_seq<C, R0 + 1, CNT - 1>(xp, WIN);
    }
}

// Output row R = C*CHROWS + I; tap j reads input row R-31+j -> slot (I+j)%40.
// Prefix-zero taps (R < 31, j < 31-R) skipped at compile time. NT store
// (R7: normal stores evict X from L3, 95 -> 122 us).
template<int C, int I>
__device__ __forceinline__ void comp_row(f2_t* __restrict__ op,
                                         const f4_t* w4,
                                         const f2_t (&WIN)[WSLOTS]) {
    constexpr int R     = C * CHROWS + I;
    constexpr int jmin_ = (R < LENM) ? (LENM - 1 - R) : 0;
    f2_t acc; acc.x = 0.f; acc.y = 0.f;
#pragma unroll
    for (int q = 0; q < 8; ++q) {
        if (q * 4 + 3 >= jmin_) {           // folds: q, jmin_ constants
            f4_t w = w4[R * 8 + q];
#pragma unroll
            for (int m = 0; m < 4; ++m) {
                const int j = q * 4 + m;
                if (j >= jmin_) {
                    f2_t xv = WIN[(I + j) % WSLOTS];
                    float wm = (m == 0) ? w.x : (m == 1) ? w.y
                             : (m == 2) ? w.z : w.w;
                    acc.x = fmaf(wm, xv.x, acc.x);
                    acc.y = fmaf(wm, xv.y, acc.y);
                }
            }
        }
    }
    __builtin_nontemporal_store(acc, &op[(size_t)R * (NCOL / 2)]);
}

template<int C, int I>
__device__ __forceinline__ void run_steps(const f2_t* __restrict__ xp,
                                          f2_t* __restrict__ op,
                                          const f4_t* w4,
                                          f2_t (&WIN)[WSLOTS]) {
    if constexpr (I < CHROWS) {
        if constexpr (I + LA < CHROWS)
            load_in<C, C * CHROWS + I + LA>(xp, WIN);   // lookahead load
        comp_row<C, I>(op, w4, WIN);
        run_steps<C, I + 1>(xp, op, w4, WIN);
    }
}

template<int C>
__device__ __forceinline__ void run_chunk(const f2_t* __restrict__ xp,
                                          f2_t* __restrict__ op,
                                          const f4_t* w4,
                                          f2_t (&WIN)[WSLOTS]) {
    // Prologue burst: all history rows + LA lookahead, back-to-back
    // (39 loads in flight for C>0 — fill-kernel-like MLP).
    if constexpr (C == 0) load_seq<0, 0, LA>(xp, WIN);
    else                  load_seq<C, C * CHROWS - (LENM - 1), (LENM - 1) + LA>(xp, WIN);
    run_steps<C, 0>(xp, op, w4, WIN);
}

// Kernel 2: sliding-window mix. T split into 4 row-chunks across blocks
// (grid 4096 = 16 blocks/CU -> occupancy no longer grid-capped at 8 waves;
// R8 post-mortem: occupancy was grid-limited, not VGPR-limited). Each
// thread owns 2 adjacent columns (f2, ~100 VGPR incl. 40-slot window).
// Chunk boundaries re-read 31 rows; adjacent blocks read them near-
// simultaneously -> L2/L3 hits, HBM traffic ~unchanged.
__global__ __launch_bounds__(256, 4) void band_mix_kernel(
    const float* __restrict__ X,
    const float* __restrict__ Wc,
    float* __restrict__ out) {
    __shared__ f4_t w4[T_ * LENM / 4];   // 1024 f4 = 16 KB
    for (int i = threadIdx.x; i < T_ * LENM / 4; i += 256)
        w4[i] = reinterpret_cast<const f4_t*>(Wc)[i];
    __syncthreads();

    const int ch     = blockIdx.x & (NCHUNK - 1);   // chunk fast-varying:
    const int colgrp = blockIdx.x >> 2;             // co-scheduled neighbors share boundary rows
    const int c = (colgrp * 256 + threadIdx.x) * 2;
    const f2_t* xp = reinterpret_cast<const f2_t*>(X + c);
    f2_t* op = reinterpret_cast<f2_t*>(out + c);

    f2_t WIN[WSLOTS];
    switch (ch) {
        case 0: run_chunk<0>(xp, op, w4, WIN); break;
        case 1: run_chunk<1>(xp, op, w4, WIN); break;
        case 2: run_chunk<2>(xp, op, w4, WIN); break;
        case 3: run_chunk<3>(xp, op, w4, WIN); break;
    }
}

extern "C" void kernel_launch(void* const* d_in, const int* in_sizes, int n_in,
                              void* d_out, int out_size, void* d_ws, size_t ws_size,
                              hipStream_t stream) {
    const float* X     = (const float*)d_in[0];
    const float* M_pad = (const float*)d_in[1];
    const float* M_big = (const float*)d_in[2];
    float* out = (float*)d_out;
    float* Wc  = (float*)d_ws;   // 128*32*4 = 16 KB scratch

    build_w_kernel<<<1, 128, 0, stream>>>(M_pad, M_big, Wc);
    band_mix_kernel<<<(NCOL / 2 / 256) * NCHUNK, 256, 0, stream>>>(X, Wc, out);
}

// Round 11
// 102.665 us; speedup vs baseline: 1.3844x; 1.3844x over previous
//
#include <hip/hip_runtime.h>
#include <math.h>

#define T_     128
#define LENM   32
#define NCOL   (8192 * 64)   // N*F = 524288 floats per timestep row
#define WSLOTS 40            // rolling register window (32 history + 8 incoming)
#define GRP    8             // rows per DMA group
#define NGRP   (T_ / GRP)    // 16 groups

typedef float f4_t __attribute__((ext_vector_type(4)));

// Kernel 1: build ALIGNED compact weights Wc[128][32] in d_ws.
// Wc[t][j] multiplies source row (t-31+j); zero when that row < 0.
__global__ void build_w_kernel(const float* __restrict__ M_pad,
                               const float* __restrict__ M_big,
                               float* __restrict__ Wc) {
    int t = threadIdx.x;
    if (t >= T_) return;
    const float* src;
    int len, joff;
    if (t < LENM)       { src = M_pad + t * LENM;              len = t + 1; joff = LENM - 1 - t; }
    else if (t == LENM) { src = M_pad + (LENM - 1) * LENM;     len = LENM;  joff = 0; }
    else                { src = M_big + (t - LENM - 1) * LENM; len = LENM;  joff = 0; }

    float m = -3.4e38f;
    for (int j = 0; j < len; ++j) m = fmaxf(m, src[j]);
    float e[LENM];
    float s = 0.f;
    for (int j = 0; j < len; ++j) { e[j] = expf(src[j] - m); s += e[j]; }
    float inv = 1.f / s;
    for (int j = 0; j < LENM; ++j) Wc[t * LENM + j] = 0.f;
    for (int j = 0; j < len; ++j)  Wc[t * LENM + joff + j] = e[j] * inv;
}

// ---- DMA staging: global -> LDS (no VGPR destination, deep in-flight) ----
// Lane tid stages its own 16B at buf[(ROW%GRP)*256+tid]; it later reads back
// ONLY those bytes -> no cross-lane sharing, no __syncthreads. The ONLY
// required sync is an explicit counted vmcnt before the pull (R10 failed
// because the compiler does NOT emit a vmcnt wait for the async LDS write ->
// ds_read dependency; barriers normally hide this via their vmcnt(0) drain).

template<int ROW>
__device__ __forceinline__ void dma_row(const float* __restrict__ xg,
                                        f4_t (&buf)[GRP * 256], int tid) {
    __builtin_amdgcn_global_load_lds(
        (const __attribute__((address_space(1))) void*)(xg + (size_t)ROW * NCOL),
        (__attribute__((address_space(3))) void*)&buf[(ROW % GRP) * 256 + tid],
        16, 0, 0);
}

template<int R0, int CNT>
__device__ __forceinline__ void dma_rows(const float* __restrict__ xg,
                                         f4_t (&buf)[GRP * 256], int tid) {
    if constexpr (CNT > 0) {
        dma_row<R0>(xg, buf, tid);
        dma_rows<R0 + 1, CNT - 1>(xg, buf, tid);
    }
}

template<int ROW>
__device__ __forceinline__ void pull_row(const f4_t (&buf)[GRP * 256], int tid,
                                         f4_t (&W)[WSLOTS]) {
    W[ROW % WSLOTS] = buf[(ROW % GRP) * 256 + tid];
}

template<int R0, int CNT>
__device__ __forceinline__ void pull_rows(const f4_t (&buf)[GRP * 256], int tid,
                                          f4_t (&W)[WSLOTS]) {
    if constexpr (CNT > 0) {
        pull_row<R0>(buf, tid, W);
        pull_rows<R0 + 1, CNT - 1>(buf, tid, W);
    }
}

// Output row ROW: tap j reads input row ROW-31+j -> slot (row+80)%40.
// Prefix-zero taps skipped at compile time. NT store (R7: normal stores
// evict X from L3, 95 -> 122 us).
template<int ROW>
__device__ __forceinline__ void comp_row(f4_t* __restrict__ op,
                                         const f4_t* w4,
                                         const f4_t (&W)[WSLOTS]) {
    constexpr int jmin_ = (ROW < LENM) ? (LENM - 1 - ROW) : 0;
    f4_t acc; acc.x = 0.f; acc.y = 0.f; acc.z = 0.f; acc.w = 0.f;
#pragma unroll
    for (int q = 0; q < 8; ++q) {
        if (q * 4 + 3 >= jmin_) {            // folds: q, jmin_ constants
            f4_t w = w4[ROW * 8 + q];
#pragma unroll
            for (int m = 0; m < 4; ++m) {
                const int j = q * 4 + m;
                if (j >= jmin_) {
                    f4_t xv = W[(ROW - (LENM - 1) + j + 2 * WSLOTS) % WSLOTS];
                    float wm = (m == 0) ? w.x : (m == 1) ? w.y
                             : (m == 2) ? w.z : w.w;
                    acc.x = fmaf(wm, xv.x, acc.x);
                    acc.y = fmaf(wm, xv.y, acc.y);
                    acc.z = fmaf(wm, xv.z, acc.z);
                    acc.w = fmaf(wm, xv.w, acc.w);
                }
            }
        }
    }
    __builtin_nontemporal_store(acc, &op[(size_t)ROW * (NCOL / 4)]);
}

template<int R0, int CNT>
__device__ __forceinline__ void comp_rows(f4_t* __restrict__ op,
                                          const f4_t* w4,
                                          const f4_t (&W)[WSLOTS]) {
    if constexpr (CNT > 0) {
        comp_row<R0>(op, w4, W);
        comp_rows<R0 + 1, CNT - 1>(op, w4, W);
    }
}

// Group G schedule: {wait vmcnt -> pull G -> dma G+1 -> comp G}.
//  * wait: at this point the vmem ops newer than dma-G are exactly comp
//    G-1's 8 NT stores -> vmcnt(8) guarantees dma-G's LDS data landed
//    (G=0: only the prologue DMAs are outstanding -> vmcnt(0)).
//  * WAR safety on buffers: comp G's FMAs force an lgkmcnt wait on pull
//    G's ds_reads, and dma G+2 is issued after comp G in program order ->
//    pull-G reads always complete before dma G+2's data can land.
template<int G>
__device__ __forceinline__ void run_group(const float* __restrict__ xg,
                                          f4_t* __restrict__ op,
                                          const f4_t* w4,
                                          f4_t (&bufA)[GRP * 256],
                                          f4_t (&bufB)[GRP * 256],
                                          int tid, f4_t (&W)[WSLOTS]) {
    if constexpr (G == 0) asm volatile("s_waitcnt vmcnt(0)" ::: "memory");
    else                  asm volatile("s_waitcnt vmcnt(8)" ::: "memory");
    __builtin_amdgcn_sched_barrier(0);      // rule #18: pin pulls below wait
    if constexpr (G & 1) pull_rows<G * GRP, GRP>(bufB, tid, W);
    else                 pull_rows<G * GRP, GRP>(bufA, tid, W);
    __builtin_amdgcn_sched_barrier(0);      // pulls above next dma issue
    if constexpr (G + 1 < NGRP) {
        if constexpr ((G + 1) & 1) dma_rows<(G + 1) * GRP, GRP>(xg, bufB, tid);
        else                       dma_rows<(G + 1) * GRP, GRP>(xg, bufA, tid);
    }
    __builtin_amdgcn_sched_barrier(0);      // dma issue stays ahead of comp
    comp_rows<G * GRP, GRP>(op, w4, W);
}

template<int G>
__device__ __forceinline__ void run_groups(const float* __restrict__ xg,
                                           f4_t* __restrict__ op,
                                           const f4_t* w4,
                                           f4_t (&bufA)[GRP * 256],
                                           f4_t (&bufB)[GRP * 256],
                                           int tid, f4_t (&W)[WSLOTS]) {
    if constexpr (G < NGRP) {
        run_group<G>(xg, op, w4, bufA, bufB, tid, W);
        run_groups<G + 1>(xg, op, w4, bufA, bufB, tid, W);
    }
}

// Kernel 2: sliding-window mix, one thread per f4-column. X rows staged via
// global_load_lds DMA (8 row-DMAs/wave in flight across each group's compute
// = 64 KB/CU vs the ~8 KB all register-window variants were stuck at),
// double-buffered LDS, 40-slot register window, LDS weights, NT stores.
__global__ __launch_bounds__(256, 2) void band_mix_kernel(
    const float* __restrict__ X,
    const float* __restrict__ Wc,
    float* __restrict__ out) {
    __shared__ f4_t w4[T_ * LENM / 4];     // 16 KB weights
    __shared__ f4_t bufA[GRP * 256];       // 32 KB stage buffer A
    __shared__ f4_t bufB[GRP * 256];       // 32 KB stage buffer B
    for (int i = threadIdx.x; i < T_ * LENM / 4; i += 256)
        w4[i] = reinterpret_cast<const f4_t*>(Wc)[i];
    __syncthreads();

    const int tid = threadIdx.x;
    const int c = (blockIdx.x * 256 + tid) * 4;
    const float* xg = X + c;
    f4_t* op = reinterpret_cast<f4_t*>(out + c);

    f4_t W[WSLOTS];
    dma_rows<0, GRP>(xg, bufA, tid);   // prologue: rows 0..7 -> bufA
    run_groups<0>(xg, op, w4, bufA, bufB, tid, W);
}

extern "C" void kernel_launch(void* const* d_in, const int* in_sizes, int n_in,
                              void* d_out, int out_size, void* d_ws, size_t ws_size,
                              hipStream_t stream) {
    const float* X     = (const float*)d_in[0];
    const float* M_pad = (const float*)d_in[1];
    const float* M_big = (const float*)d_in[2];
    float* out = (float*)d_out;
    float* Wc  = (float*)d_ws;   // 128*32*4 = 16 KB scratch

    build_w_kernel<<<1, 128, 0, stream>>>(M_pad, M_big, Wc);
    band_mix_kernel<<<NCOL / 4 / 256, 256, 0, stream>>>(X, Wc, out);
}

// Round 12
// 102.443 us; speedup vs baseline: 1.3874x; 1.0022x over previous
//
#include <hip/hip_runtime.h>
#include <math.h>

#define T_    128
#define LENM  32
#define NCOL  (8192 * 64)   // N*F = 524288 floats per timestep row

typedef float f4_t __attribute__((ext_vector_type(4)));

// Kernel 1: build ALIGNED compact weights Wc[128][32] in d_ws.
// Wc[t][j] multiplies source row (t-31+j); zero when that row < 0.
__global__ void build_w_kernel(const float* __restrict__ M_pad,
                               const float* __restrict__ M_big,
                               float* __restrict__ Wc) {
    int t = threadIdx.x;
    if (t >= T_) return;
    const float* src;
    int len, joff;
    if (t < LENM)       { src = M_pad + t * LENM;              len = t + 1; joff = LENM - 1 - t; }
    else if (t == LENM) { src = M_pad + (LENM - 1) * LENM;     len = LENM;  joff = 0; }
    else                { src = M_big + (t - LENM - 1) * LENM; len = LENM;  joff = 0; }

    float m = -3.4e38f;
    for (int j = 0; j < len; ++j) m = fmaxf(m, src[j]);
    float e[LENM];
    float s = 0.f;
    for (int j = 0; j < len; ++j) { e[j] = expf(src[j] - m); s += e[j]; }
    float inv = 1.f / s;
    for (int j = 0; j < LENM; ++j) Wc[t * LENM + j] = 0.f;
    for (int j = 0; j < len; ++j)  Wc[t * LENM + joff + j] = e[j] * inv;
}

#define LOOKAHEAD 8

// Fully-bypassing store: nt (L2 non-temporal) + sc0 sc1 (system scope, no
// L3/MALL allocation). Theory: __builtin_nontemporal_store still ALLOCATES
// in the 256MiB L3 -> out (256MB) evicts half of X (256MB, exactly L3-sized)
// -> the invariant FETCH_SIZE = 131MB = 51% of X across all rounds.
__device__ __forceinline__ void store_bypass(f4_t* p, f4_t v) {
    asm volatile("global_store_dwordx4 %0, %1, off nt sc0 sc1"
                 :: "v"(p), "v"(v) : "memory");
}

// One pipeline step for output row R (compile-time). Chunk K = R/32 uses
// window buffer CUR=(K&1?B:A), previous chunk's buffer is PRV. Issues the
// global load of row R+LOOKAHEAD into its statically-known slot, then
// computes output R (prefix-zero taps skipped at compile time).
template<int R>
__device__ __forceinline__ void step(const f4_t* __restrict__ xp,
                                     f4_t* __restrict__ op,
                                     const f4_t* w4,
                                     f4_t (&A)[LENM], f4_t (&B)[LENM]) {
    constexpr int K     = R / LENM;
    constexpr int i_    = R % LENM;
    constexpr int jmin_ = (R < LENM) ? (LENM - 1 - i_) : 0;
    f4_t (&CUR)[LENM] = (K & 1) ? B : A;
    f4_t (&PRV)[LENM] = (K & 1) ? A : B;
    const size_t rs = NCOL / 4;   // row stride in f4 units

    if constexpr (R + LOOKAHEAD < T_) {
        f4_t ld = xp[(size_t)(R + LOOKAHEAD) * rs];
        if constexpr (i_ < LENM - LOOKAHEAD) CUR[i_ + LOOKAHEAD] = ld;
        else                                 PRV[i_ - (LENM - LOOKAHEAD)] = ld;
    }

    f4_t acc; acc.x = 0.f; acc.y = 0.f; acc.z = 0.f; acc.w = 0.f;
#pragma unroll
    for (int q = 0; q < 8; ++q) {
        if (q * 4 + 3 >= jmin_) {            // folds: q, jmin_ constants
            f4_t w = w4[R * 8 + q];
#pragma unroll
            for (int m = 0; m < 4; ++m) {
                const int j = q * 4 + m;
                if (j >= jmin_) {
                    f4_t xv = (j < LENM - 1 - i_) ? PRV[i_ + 1 + j]
                                                  : CUR[i_ + j - (LENM - 1)];
                    float wm = (m == 0) ? w.x : (m == 1) ? w.y
                             : (m == 2) ? w.z : w.w;
                    acc.x = fmaf(wm, xv.x, acc.x);
                    acc.y = fmaf(wm, xv.y, acc.y);
                    acc.z = fmaf(wm, xv.z, acc.z);
                    acc.w = fmaf(wm, xv.w, acc.w);
                }
            }
        }
    }
    store_bypass(&op[(size_t)R * rs], acc);
}

template<int R>
__device__ __forceinline__ void run_steps(const f4_t* __restrict__ xp,
                                          f4_t* __restrict__ op,
                                          const f4_t* w4,
                                          f4_t (&A)[LENM], f4_t (&B)[LENM]) {
    if constexpr (R < T_) {
        step<R>(xp, op, w4, A, B);
        run_steps<R + 1>(xp, op, w4, A, B);
    }
}

// Kernel 2: sliding-window mix. Each thread owns 4 adjacent columns (float4).
// R4 structure (best, 95.3us) with ONE variable changed: the output store
// now fully bypasses L2+L3 (nt sc0 sc1) so out lines cannot evict X from
// the L3 (X = 256MiB = exactly L3 capacity -> full residency across the
// graph-replay loop if nothing competes).
__global__ __launch_bounds__(256, 2) void band_mix_kernel(
    const float* __restrict__ X,
    const float* __restrict__ Wc,
    float* __restrict__ out) {
    __shared__ f4_t w4[T_ * LENM / 4];   // 1024 f4 = 16 KB
    for (int i = threadIdx.x; i < T_ * LENM / 4; i += 256)
        w4[i] = reinterpret_cast<const f4_t*>(Wc)[i];
    __syncthreads();

    const int c = (blockIdx.x * 256 + threadIdx.x) * 4;
    const f4_t* xp = reinterpret_cast<const f4_t*>(X + c);
    f4_t* op = reinterpret_cast<f4_t*>(out + c);
    const size_t rs = NCOL / 4;

    f4_t A[LENM], B[LENM];
    // prologue: rows 0..7 into A (chunk 0 never reads PRV; B needs no init)
#pragma unroll
    for (int i = 0; i < LOOKAHEAD; ++i) A[i] = xp[(size_t)i * rs];

    run_steps<0>(xp, op, w4, A, B);
}

extern "C" void kernel_launch(void* const* d_in, const int* in_sizes, int n_in,
                              void* d_out, int out_size, void* d_ws, size_t ws_size,
                              hipStream_t stream) {
    const float* X     = (const float*)d_in[0];
    const float* M_pad = (const float*)d_in[1];
    const float* M_big = (const float*)d_in[2];
    float* out = (float*)d_out;
    float* Wc  = (float*)d_ws;   // 128*32*4 = 16 KB scratch

    build_w_kernel<<<1, 128, 0, stream>>>(M_pad, M_big, Wc);
    band_mix_kernel<<<NCOL / 4 / 256, 256, 0, stream>>>(X, Wc, out);
}